// Round 1
// baseline (110.423 us; speedup 1.0000x reference)
//
#include <hip/hip_runtime.h>
#include <math.h>

// QuantumLayer: B=512, Q=14 qubits (state 2^14=16384 fp32), L=2 layers.
//
// Key algebraic reductions vs. the reference:
//  * RY(x_i) followed immediately by RY(w0_i) on the same wire = RY(x_i+w0_i)
//    -> state entering first CNOT chain is a PRODUCT state, filled directly.
//  * CNOT chain (ctrl i -> i+1, i=0..Q-2) is the prefix-XOR permutation:
//    state_new[m] = state_old[m ^ (m>>1)]  (wire 0 = MSB). Chain #1 is folded
//    into the fill's gather index; chain #2 is folded into the measurement
//    as a prefix-parity sign. Only the middle RY(w1) layer sweeps the state.
//  * out[b,i] = sum_n state[n]^2 * (1 - 2*parity(n >> (Q-1-i)))
//
// One block per batch element; 64 KB LDS statevector -> 2 blocks/CU.

#define Q 14
#define NSTATE (1 << Q)        // 16384
#define BLOCK 256
#define PER_THREAD (NSTATE / BLOCK)  // 64
#define NPAIR_IT (NSTATE / 2 / BLOCK) // 32

__global__ __launch_bounds__(BLOCK, 2)
void quantum_kernel(const float* __restrict__ x,   // [B, Q]
                    const float* __restrict__ w,   // [2, Q]
                    float* __restrict__ out)       // [B, Q]
{
    __shared__ float state[NSTATE];
    __shared__ float c0[Q], s0[Q], c1[Q], s1[Q];
    __shared__ float red[4 * Q];

    const int b = blockIdx.x;
    const int tid = threadIdx.x;

    if (tid < Q) {
        float a0 = 0.5f * (x[b * Q + tid] + w[tid]);        // merged RY(x)+RY(w0)
        c0[tid] = cosf(a0);
        s0[tid] = sinf(a0);
        float a1 = 0.5f * w[Q + tid];                       // layer-2 weights
        c1[tid] = cosf(a1);
        s1[tid] = sinf(a1);
    }
    __syncthreads();

    // Snapshot per-wire cos/sin into registers (avoid re-reading LDS 64x).
    float rc0[Q], rs0[Q];
#pragma unroll
    for (int i = 0; i < Q; ++i) { rc0[i] = c0[i]; rs0[i] = s0[i]; }

    // Fill: state[m] = prod_i f_i(bit of wire i of g), g = m ^ (m>>1)
    // (product state pushed through CNOT chain #1).
    // n = j*BLOCK + tid keeps lane-stride-1 LDS writes (conflict-free).
    for (int j = 0; j < PER_THREAD; ++j) {
        int m = j * BLOCK + tid;
        int g = m ^ (m >> 1);
        float amp = 1.0f;
#pragma unroll
        for (int i = 0; i < Q; ++i) {
            amp *= ((g >> (Q - 1 - i)) & 1) ? rs0[i] : rc0[i];
        }
        state[m] = amp;
    }
    __syncthreads();

    // Middle RY(w1) layer: one butterfly pass per wire, bit position p = Q-1-i.
    for (int i = 0; i < Q; ++i) {
        const int p = Q - 1 - i;
        const float c = c1[i], s = s1[i];
        for (int k = 0; k < NPAIR_IT; ++k) {
            int q = k * BLOCK + tid;
            int n0 = ((q >> p) << (p + 1)) | (q & ((1 << p) - 1));
            int n1 = n0 | (1 << p);
            float a = state[n0];
            float bb = state[n1];
            state[n0] = c * a - s * bb;
            state[n1] = s * a + c * bb;
        }
        __syncthreads();
    }

    // Measurement with CNOT chain #2 folded in as prefix parity:
    // out_i += state[n]^2 * (1 - 2*parity(n >> (Q-1-i)))
    float acc[Q];
#pragma unroll
    for (int i = 0; i < Q; ++i) acc[i] = 0.0f;

    for (int j = 0; j < PER_THREAD; ++j) {
        int n = j * BLOCK + tid;
        float v = state[n];
        float p2 = v * v;
        int par = 0;
#pragma unroll
        for (int i = 0; i < Q; ++i) {
            par ^= (n >> (Q - 1 - i)) & 1;
            acc[i] += par ? -p2 : p2;
        }
    }

    // Reduce across the block: wave(64)-shuffle, then 4 partials in LDS.
#pragma unroll
    for (int i = 0; i < Q; ++i) {
        float v = acc[i];
        for (int off = 32; off > 0; off >>= 1)
            v += __shfl_down(v, off, 64);
        acc[i] = v;
    }
    const int wave = tid >> 6;
    const int lane = tid & 63;
    if (lane == 0) {
#pragma unroll
        for (int i = 0; i < Q; ++i) red[wave * Q + i] = acc[i];
    }
    __syncthreads();
    if (tid < Q) {
        out[b * Q + tid] = red[tid] + red[Q + tid] + red[2 * Q + tid] + red[3 * Q + tid];
    }
}

extern "C" void kernel_launch(void* const* d_in, const int* in_sizes, int n_in,
                              void* d_out, int out_size, void* d_ws, size_t ws_size,
                              hipStream_t stream) {
    const float* x = (const float*)d_in[0];   // [B, Q] fp32
    const float* w = (const float*)d_in[1];   // [2, Q] fp32
    float* out = (float*)d_out;               // [B, Q] fp32
    const int B = in_sizes[0] / Q;            // 512
    quantum_kernel<<<dim3(B), dim3(BLOCK), 0, stream>>>(x, w, out);
}

// Round 2
// 69.364 us; speedup vs baseline: 1.5919x; 1.5919x over previous
//
#include <hip/hip_runtime.h>
#include <math.h>

// QuantumLayer B=512, Q=14. State 2^14 fp32 held in REGISTERS: 64/thread x 256 threads.
//
// Index spaces (m = state index, bit 13 = wire 0 = MSB):
//  Phase A ownership: r = m[13:8] (thread-local, 64 regs), lane = m[7:2], wave = m[1:0]
//    -> RY passes on wires 0..5 (m bits 13..8) are register-local, compile-time indices.
//  One LDS transpose (scatter-write b32 / contiguous read) to
//  Phase B ownership: u = m[7:2] (thread-local), lane' = {m13..m10, m1, m0}, wave' = m[9:8]
//    -> passes on wires 6..11 register-local; wires 12,13 via __shfl_xor(2/1).
//  Fill: product state merged RY(x+w0) pushed through CNOT chain #1 (g = m ^ (m>>1)),
//    built as a 6-level product tree (~130 mults vs 64x14 selects).
//  Measurement: chain #2 folded as prefix parity; local parities are compile-time
//    signs in the unrolled loop; high-bit parities are thread-uniform signs.
//
// LDS chunk stride 68 floats (272 B): scatter writes land (const + lane) -> 2-way (free);
// contiguous reads vectorize to b128 with balanced banks (4*(lane+q) mod 32).

#define Q 14
#define BLOCK 256
#define SCHUNK 68

__global__ __launch_bounds__(BLOCK, 2)
void quantum_kernel(const float* __restrict__ x,   // [B,14]
                    const float* __restrict__ w,   // [2,14]
                    float* __restrict__ out)       // [B,14]
{
    __shared__ float lds[256 * SCHUNK];   // 69632 B
    __shared__ float2 cs0[Q], cs1[Q];
    __shared__ float red[4 * Q];

    const int b = blockIdx.x;
    const int tid = threadIdx.x;
    const int wv = tid >> 6;    // wave index (2 bits)
    const int lane = tid & 63;

    if (tid < Q) {
        float a0 = 0.5f * (x[b * Q + tid] + w[tid]);   // RY(x)·RY(w0) merged
        cs0[tid] = make_float2(cosf(a0), sinf(a0));
        float a1 = 0.5f * w[Q + tid];
        cs1[tid] = make_float2(cosf(a1), sinf(a1));
    }
    __syncthreads();

    float2 f[Q];
#pragma unroll
    for (int i = 0; i < Q; ++i) f[i] = cs0[i];

    // ---- Fill (phase A): m = (r<<8) | (lane<<2) | wv;  g = m ^ (m>>1)
    // factor for g bit j is (g_j ? sin : cos) of wire 13-j.
    const int mlow = (lane << 2) | wv;     // m bits 7..0
    float H = 1.0f;                        // wires 13..7 (g bits 0..6): thread-uniform
#pragma unroll
    for (int j = 0; j <= 6; ++j) {
        int gj = ((mlow >> (j + 1)) ^ (mlow >> j)) & 1;
        H *= gj ? f[13 - j].y : f[13 - j].x;
    }
    const int b7 = (mlow >> 7) & 1;        // g7 = r0 ^ b7 (wire 6)
    float F7_0 = b7 ? f[6].y : f[6].x;
    float F7_1 = b7 ? f[6].x : f[6].y;

    float t1[2], t2[4], t3[8], t4[16], t5[32], st[64];
    t1[0] = H * F7_0;  t1[1] = H * F7_1;
#pragma unroll
    for (int r = 0; r < 4; ++r) {          // g8 = r1^r0, wire 5
        int g = ((r >> 1) ^ r) & 1;
        t2[r] = t1[r & 1] * (g ? f[5].y : f[5].x);
    }
#pragma unroll
    for (int r = 0; r < 8; ++r) {          // g9 = r2^r1, wire 4
        int g = ((r >> 2) ^ (r >> 1)) & 1;
        t3[r] = t2[r & 3] * (g ? f[4].y : f[4].x);
    }
#pragma unroll
    for (int r = 0; r < 16; ++r) {         // g10 = r3^r2, wire 3
        int g = ((r >> 3) ^ (r >> 2)) & 1;
        t4[r] = t3[r & 7] * (g ? f[3].y : f[3].x);
    }
#pragma unroll
    for (int r = 0; r < 32; ++r) {         // g11 = r4^r3, wire 2
        int g = ((r >> 4) ^ (r >> 3)) & 1;
        t5[r] = t4[r & 15] * (g ? f[2].y : f[2].x);
    }
    float FF[2][2];                        // f13(r5)[wire0] * f12(r5^r4)[wire1]
    FF[0][0] = f[0].x * f[1].x;
    FF[0][1] = f[0].x * f[1].y;
    FF[1][0] = f[0].y * f[1].y;
    FF[1][1] = f[0].y * f[1].x;
#pragma unroll
    for (int r = 0; r < 64; ++r)
        st[r] = t5[r & 31] * FF[(r >> 5) & 1][(r >> 4) & 1];

    // ---- Passes wires 0..5: register-local butterflies on r bit (5-i)
#pragma unroll
    for (int i = 0; i < 6; ++i) {
        const int bit = 5 - i;
        float2 cs = cs1[i];
        const float c = cs.x, s = cs.y;
#pragma unroll
        for (int k = 0; k < 32; ++k) {
            int r0 = ((k >> bit) << (bit + 1)) | (k & ((1 << bit) - 1));
            int r1 = r0 | (1 << bit);
            float a = st[r0], bb = st[r1];
            st[r0] = c * a - s * bb;
            st[r1] = s * a + c * bb;
        }
    }

    // ---- Transpose to phase B ownership.
    // element r of A-thread (wv,lane) -> chunk ftb = (r&3)*64 + ((r>>2)<<2) + wv, slot=lane
    {
        const int wbase = wv * SCHUNK + lane;
#pragma unroll
        for (int r = 0; r < 64; ++r) {
            int ct = ((r & 3) * 64 + ((r >> 2) << 2)) * SCHUNK;
            lds[wbase + ct] = st[r];
        }
    }
    __syncthreads();
    {
        const int rbase = tid * SCHUNK;    // B-thread's chunk is contiguous
#pragma unroll
        for (int u = 0; u < 64; ++u) st[u] = lds[rbase + u];
    }

    // ---- Passes wires 6..11: register-local on u bit (11-i)
#pragma unroll
    for (int i = 6; i < 12; ++i) {
        const int bit = 11 - i;
        float2 cs = cs1[i];
        const float c = cs.x, s = cs.y;
#pragma unroll
        for (int k = 0; k < 32; ++k) {
            int r0 = ((k >> bit) << (bit + 1)) | (k & ((1 << bit) - 1));
            int r1 = r0 | (1 << bit);
            float a = st[r0], bb = st[r1];
            st[r0] = c * a - s * bb;
            st[r1] = s * a + c * bb;
        }
    }

    // ---- Passes wires 12,13: lane-bit exchanges via shfl_xor (m1 = lane bit1, m0 = bit0)
    {
        float2 cs = cs1[12];
        float ssgn = ((lane >> 1) & 1) ? cs.y : -cs.y;
#pragma unroll
        for (int u = 0; u < 64; ++u) {
            float pv = __shfl_xor(st[u], 2, 64);
            st[u] = cs.x * st[u] + ssgn * pv;
        }
    }
    {
        float2 cs = cs1[13];
        float ssgn = (lane & 1) ? cs.y : -cs.y;
#pragma unroll
        for (int u = 0; u < 64; ++u) {
            float pv = __shfl_xor(st[u], 1, 64);
            st[u] = cs.x * st[u] + ssgn * pv;
        }
    }

    // ---- Measurement: out_i = sum p2 * (-1)^parity(m >> (13-i)), chain #2 folded.
    // acc[0] = sum p2; acc[k] = sum p2 * (-1)^parity(top k bits of u), k=1..6
    float acc[7];
#pragma unroll
    for (int k = 0; k < 7; ++k) acc[k] = 0.0f;
#pragma unroll
    for (int u = 0; u < 64; ++u) {
        float p2 = st[u] * st[u];
        acc[0] += p2;
#pragma unroll
        for (int k = 1; k <= 6; ++k) {
            int par = __builtin_popcount(u >> (6 - k)) & 1;   // compile-time sign
            acc[k] += par ? -p2 : p2;
        }
    }

    // thread-uniform high-bit signs: h = m[13:8] = ((lane>>2)<<2) | wv
    const int h = ((lane >> 2) << 2) | wv;
    float v[Q];
#pragma unroll
    for (int i = 0; i < 6; ++i) {
        int par = __builtin_popcount(h >> (5 - i)) & 1;
        v[i] = par ? -acc[0] : acc[0];
    }
    const int P6 = __builtin_popcount(h) & 1;
#pragma unroll
    for (int i = 6; i < 12; ++i)
        v[i] = P6 ? -acc[i - 5] : acc[i - 5];
    const int p12 = P6 ^ ((lane >> 1) & 1);
    const int p13 = p12 ^ (lane & 1);
    v[12] = p12 ? -acc[6] : acc[6];
    v[13] = p13 ? -acc[6] : acc[6];

    // ---- Block reduction
#pragma unroll
    for (int i = 0; i < Q; ++i) {
        float t = v[i];
        for (int off = 32; off > 0; off >>= 1) t += __shfl_down(t, off, 64);
        v[i] = t;
    }
    if (lane == 0) {
#pragma unroll
        for (int i = 0; i < Q; ++i) red[wv * Q + i] = v[i];
    }
    __syncthreads();
    if (tid < Q)
        out[b * Q + tid] = red[tid] + red[Q + tid] + red[2 * Q + tid] + red[3 * Q + tid];
}

extern "C" void kernel_launch(void* const* d_in, const int* in_sizes, int n_in,
                              void* d_out, int out_size, void* d_ws, size_t ws_size,
                              hipStream_t stream) {
    const float* x = (const float*)d_in[0];
    const float* w = (const float*)d_in[1];
    float* out = (float*)d_out;
    const int B = in_sizes[0] / Q;   // 512
    quantum_kernel<<<dim3(B), dim3(BLOCK), 0, stream>>>(x, w, out);
}